// Round 3
// baseline (379.003 us; speedup 1.0000x reference)
//
#include <hip/hip_runtime.h>

// RegressionWisard predict (centrality='mean')
//   input:  [B=4096, E=8192] int32 bits
//   map:    [E] permutation int32
//   counts: [N=512, 65536] int32  (values 0..3 per problem setup)
//   sums:   [N=512, 65536] float32
//   out:    [B] float32 = nan_to_num(sum(s where c>0) / sum(c where c>0))
//
// R3: queue-limited random-gather regime (R2: 2.3 TB/s, +MLP gave only 6%).
// (1) prepass packs counts int32->uint8 into d_ws (32 MB, L3-resident ->
//     counts gathers become fast L3 hits, freeing miss-queue slots),
// (2) sums loads conditional on c>0 (25% fewer HBM-random requests).

constexpr int BATCH   = 4096;
constexpr int ENTRY   = 8192;
constexpr int TUP     = 16;
constexpr int NEUR    = ENTRY / TUP;   // 512
constexpr int THREADS = 256;
constexpr int SPB     = 2;             // samples per block
constexpr size_t CTAB_ELEMS = (size_t)NEUR * 65536;   // 32M counts

// ---- Prepass: counts int32 -> uint8 (values 0..3 fit trivially) ----
__global__ __launch_bounds__(256) void pack_counts_kernel(
    const int4* __restrict__ src, uchar4* __restrict__ dst)
{
    const size_t i = (size_t)blockIdx.x * 256 + threadIdx.x;   // 8M int4s
    const int4 v = src[i];
    dst[i] = make_uchar4((unsigned char)v.x, (unsigned char)v.y,
                         (unsigned char)v.z, (unsigned char)v.w);
}

// ---- Main kernel (templated on counts type for the no-ws fallback) ----
template <typename CT>
__global__ __launch_bounds__(THREADS) void wisard_kernel(
    const int*   __restrict__ input,
    const int*   __restrict__ mapping,
    const CT*    __restrict__ counts,
    const float* __restrict__ sums,
    float*       __restrict__ out)
{
    __shared__ unsigned int packed[SPB][ENTRY / 32];   // 2 KB bit-packed rows
    __shared__ float s_resp[SPB][THREADS / 64];
    __shared__ int   s_cnt [SPB][THREADS / 64];

    const int tid  = threadIdx.x;
    const int lane = tid & 63;
    const int wv   = tid >> 6;
    const int b0   = blockIdx.x * SPB;

    // Stage 1: coalesced nontemporal input load + ballot pack
    #pragma unroll
    for (int s = 0; s < SPB; ++s) {
        const int* row = input + (size_t)(b0 + s) * ENTRY;
        #pragma unroll
        for (int i = wv; i < ENTRY / 64; i += THREADS / 64) {
            const int v = __builtin_nontemporal_load(&row[i * 64 + lane]);
            const unsigned long long m = __ballot(v & 1);
            if (lane == 0) {
                packed[s][i * 2]     = (unsigned int)(m);
                packed[s][i * 2 + 1] = (unsigned int)(m >> 32);
            }
        }
    }
    __syncthreads();

    // Stage 2: build 4 addresses (2 neurons x 2 samples)
    int idx[SPB][2];
    #pragma unroll
    for (int k = 0; k < 2; ++k) {
        const int n = tid + k * THREADS;
        const int* map_n = mapping + n * TUP;
        int addr[SPB] = {0, 0};
        #pragma unroll
        for (int t = 0; t < TUP; ++t) {
            const int j = map_n[t];               // t=0 is the MSB
            const unsigned w = j >> 5, sh = j & 31;
            #pragma unroll
            for (int s = 0; s < SPB; ++s)
                addr[s] = (addr[s] << 1) | ((packed[s][w] >> sh) & 1);
        }
        #pragma unroll
        for (int s = 0; s < SPB; ++s) idx[s][k] = (n << 16) | addr[s];
    }

    // Issue all 4 counts gathers first (fast: uint8 table is L3-resident),
    // then conditionally gather sums (cuts HBM-random requests by ~25%).
    int cv[SPB][2];
    #pragma unroll
    for (int s = 0; s < SPB; ++s)
        #pragma unroll
        for (int k = 0; k < 2; ++k)
            cv[s][k] = (int)counts[idx[s][k]];

    float resp[SPB];
    int   cnt [SPB];
    #pragma unroll
    for (int s = 0; s < SPB; ++s) {
        resp[s] = 0.0f; cnt[s] = 0;
        #pragma unroll
        for (int k = 0; k < 2; ++k) {
            const int c = cv[s][k];
            if (c > 0) {                 // exec-masked: skips the sums load
                resp[s] += sums[idx[s][k]];
                cnt [s] += c;
            }
        }
    }

    // Stage 3: per-sample block reduction
    #pragma unroll
    for (int s = 0; s < SPB; ++s) {
        float r = resp[s]; int c = cnt[s];
        #pragma unroll
        for (int off = 32; off > 0; off >>= 1) {
            r += __shfl_down(r, off, 64);
            c += __shfl_down(c, off, 64);
        }
        if (lane == 0) { s_resp[s][wv] = r; s_cnt[s][wv] = c; }
    }
    __syncthreads();
    if (tid < SPB) {
        float r = 0.0f; int c = 0;
        #pragma unroll
        for (int w = 0; w < THREADS / 64; ++w) { r += s_resp[tid][w]; c += s_cnt[tid][w]; }
        out[b0 + tid] = (c > 0) ? (r / (float)c) : 0.0f;   // nan_to_num(0/0)==0
    }
}

extern "C" void kernel_launch(void* const* d_in, const int* in_sizes, int n_in,
                              void* d_out, int out_size, void* d_ws, size_t ws_size,
                              hipStream_t stream) {
    (void)in_sizes; (void)n_in; (void)out_size;
    const int*   input   = (const int*)d_in[0];
    const int*   mapping = (const int*)d_in[1];
    const int*   counts  = (const int*)d_in[2];
    const float* sums    = (const float*)d_in[3];
    float*       out     = (float*)d_out;

    if (ws_size >= CTAB_ELEMS) {
        // Prepass: pack 32M int32 counts into 32 MB uint8 table in d_ws.
        pack_counts_kernel<<<(int)(CTAB_ELEMS / 4 / 256), 256, 0, stream>>>(
            (const int4*)counts, (uchar4*)d_ws);
        wisard_kernel<unsigned char><<<BATCH / SPB, THREADS, 0, stream>>>(
            input, mapping, (const unsigned char*)d_ws, sums, out);
    } else {
        // Fallback: gather int32 counts directly (R2 behavior).
        wisard_kernel<int><<<BATCH / SPB, THREADS, 0, stream>>>(
            input, mapping, counts, sums, out);
    }
}

// Round 5
// 378.136 us; speedup vs baseline: 1.0023x; 1.0023x over previous
//
#include <hip/hip_runtime.h>

// RegressionWisard predict (centrality='mean')
//   input:  [B=4096, E=8192] int32 bits
//   map:    [E] permutation int32
//   counts: [N=512, 65536] int32 (values 0..3)
//   sums:   [N=512, 65536] float32
//   out:    [B] float32 = nan_to_num(sum(s where c>0) / sum(c where c>0))
//
// R5 (= R4 design, compile fix): invert gather->stream. R1-R3 showed random
// table gathers are queue/latency-limited at ~2.8 TB/s effective. Structure:
// phase A computes all addresses (streaming); phase B streams each neuron's
// table slice through LDS and scatters packed (resp,cnt) via int64 atomics;
// phase C decodes. All HBM traffic coalesced streaming (~396 MB floor).
// Fix vs R4: __builtin_nontemporal_load needs true vector types, not HIP's
// float4/int4 classes -> use ext_vector_type typedefs.

typedef float f32x4 __attribute__((ext_vector_type(4)));
typedef int   i32x4 __attribute__((ext_vector_type(4)));

constexpr int BATCH   = 4096;
constexpr int ENTRY   = 8192;
constexpr int TUP     = 16;
constexpr int NEUR    = ENTRY / TUP;     // 512
constexpr int SPB_A   = 4;               // samples per phase-A block
constexpr int QSPLIT  = 8;               // address-space slices per neuron
constexpr int QSIZE   = 65536 / QSPLIT;  // 8192 entries per slice

constexpr size_t ADDR_BYTES = (size_t)NEUR * BATCH * 2;       // 4 MB uint16
constexpr size_t ACC_OFF    = ADDR_BYTES;
constexpr size_t WS_NEED    = ADDR_BYTES + (size_t)BATCH * 8; // + 32 KB acc

// ---- zero the packed accumulators (d_ws is poisoned 0xAA every call) ----
__global__ __launch_bounds__(256) void zero_acc_kernel(unsigned long long* acc) {
    acc[blockIdx.x * 256 + threadIdx.x] = 0ull;
}

// ---- Phase A: bit-pack input rows, build addr[n][b] uint16 matrix ----
__global__ __launch_bounds__(256) void phaseA_kernel(
    const int* __restrict__ input,
    const int* __restrict__ mapping,
    unsigned short* __restrict__ addr_out)
{
    __shared__ unsigned int packed[SPB_A][ENTRY / 32];   // 4 KB
    const int tid  = threadIdx.x;
    const int lane = tid & 63;
    const int wv   = tid >> 6;
    const int b0   = blockIdx.x * SPB_A;
    constexpr int CH = ENTRY / 64;                       // 128 chunks/row

    // Stage 1: 4-unrolled coalesced loads -> ballot pack (MLP for latency)
    for (int i0 = wv * 4; i0 < SPB_A * CH; i0 += 16) {
        int v[4];
        #pragma unroll
        for (int u = 0; u < 4; ++u) {
            const int i = i0 + u, r = i >> 7, c = i & 127;
            v[u] = __builtin_nontemporal_load(
                &input[(size_t)(b0 + r) * ENTRY + c * 64 + lane]);
        }
        #pragma unroll
        for (int u = 0; u < 4; ++u) {
            const int i = i0 + u, r = i >> 7, c = i & 127;
            const unsigned long long m = __ballot(v[u] & 1);
            if (lane == 0) {
                packed[r][c * 2]     = (unsigned int)(m);
                packed[r][c * 2 + 1] = (unsigned int)(m >> 32);
            }
        }
    }
    __syncthreads();

    // Stage 2: 2 neurons/thread x 4 samples; t=0 is the MSB
    #pragma unroll
    for (int k = 0; k < 2; ++k) {
        const int n = tid + k * 256;
        const int* map_n = mapping + n * TUP;
        int addr[SPB_A] = {0, 0, 0, 0};
        #pragma unroll
        for (int t = 0; t < TUP; ++t) {
            const int j = map_n[t];
            const unsigned w = j >> 5, sh = j & 31;
            #pragma unroll
            for (int s = 0; s < SPB_A; ++s)
                addr[s] = (addr[s] << 1) | ((packed[s][w] >> sh) & 1);
        }
        uint2 pk;
        pk.x = (unsigned)addr[0] | ((unsigned)addr[1] << 16);
        pk.y = (unsigned)addr[2] | ((unsigned)addr[3] << 16);
        *(uint2*)(addr_out + (size_t)n * BATCH + b0) = pk;   // 8B aligned
    }
}

// ---- Phase B: stream table slice through LDS, scatter packed atomics ----
// block = (neuron n, slice q). acc[b] += (round(s*2^24)<<20) + c for trained
// entries; Sum(c) <= 3*512 = 1536 < 2^20 so the fields never interact.
__global__ __launch_bounds__(256) void phaseB_kernel(
    const int*   __restrict__ counts,
    const float* __restrict__ sums,
    const unsigned short* __restrict__ addr,
    unsigned long long* __restrict__ acc)
{
    __shared__ float         s_tab[QSIZE];   // 32 KB
    __shared__ unsigned char c_tab[QSIZE];   //  8 KB
    const int tid = threadIdx.x;
    const int n   = blockIdx.x >> 3;
    const int q   = blockIdx.x & (QSPLIT - 1);
    const size_t base = ((size_t)n << 16) + ((size_t)q * QSIZE);

    // Stream the slice: 8 f32x4 + 8 i32x4 per thread, issued before use.
    const f32x4* s4 = (const f32x4*)(sums + base);
    const i32x4* c4 = (const i32x4*)(counts + base);
    f32x4 vs[8]; i32x4 vc[8];
    #pragma unroll
    for (int i = 0; i < 8; ++i) vs[i] = __builtin_nontemporal_load(&s4[tid + 256 * i]);
    #pragma unroll
    for (int i = 0; i < 8; ++i) vc[i] = __builtin_nontemporal_load(&c4[tid + 256 * i]);
    #pragma unroll
    for (int i = 0; i < 8; ++i) {
        ((f32x4*)s_tab)[tid + 256 * i] = vs[i];
        *(uchar4*)&c_tab[(tid + 256 * i) * 4] =
            make_uchar4((unsigned char)vc[i].x, (unsigned char)vc[i].y,
                        (unsigned char)vc[i].z, (unsigned char)vc[i].w);
    }
    __syncthreads();

    // Scan this neuron's 4096 addresses (4 MB matrix -> L3-hot re-reads).
    const unsigned short* arow = addr + ((size_t)n << 12);
    #pragma unroll
    for (int i = tid; i < BATCH; i += 256) {
        const int a = arow[i];
        if ((a >> 13) == q) {
            const int local = a & (QSIZE - 1);
            const int c = c_tab[local];
            if (c) {
                const long long r = (long long)__float2int_rn(s_tab[local] * 16777216.0f);
                atomicAdd(&acc[i], (unsigned long long)((r << 20) + (long long)c));
            }
        }
    }
}

// ---- Phase C: decode packed accumulator, divide ----
__global__ __launch_bounds__(256) void phaseC_kernel(
    const unsigned long long* __restrict__ acc, float* __restrict__ out)
{
    const int i = blockIdx.x * 256 + threadIdx.x;
    const long long v = (long long)acc[i];
    const int cnt = (int)(v & 0xFFFFF);
    const long long rq = v >> 20;   // arithmetic shift: signed resp sum
    out[i] = (cnt > 0)
        ? (float)(((double)rq * (1.0 / 16777216.0)) / (double)cnt)
        : 0.0f;                      // nan_to_num(0/0) == 0
}

// ---- Fallback (ws too small): R2-style direct gather ----
__global__ __launch_bounds__(256) void wisard_direct_kernel(
    const int* __restrict__ input, const int* __restrict__ mapping,
    const int* __restrict__ counts, const float* __restrict__ sums,
    float* __restrict__ out)
{
    __shared__ unsigned int packed[ENTRY / 32];
    __shared__ float s_resp[4];
    __shared__ int   s_cnt [4];
    const int tid = threadIdx.x, lane = tid & 63, wv = tid >> 6;
    const int* row = input + (size_t)blockIdx.x * ENTRY;
    for (int i = wv; i < ENTRY / 64; i += 4) {
        const unsigned long long m = __ballot(row[i * 64 + lane] & 1);
        if (lane == 0) {
            packed[i * 2] = (unsigned int)m;
            packed[i * 2 + 1] = (unsigned int)(m >> 32);
        }
    }
    __syncthreads();
    float resp = 0.0f; int cnt = 0;
    #pragma unroll
    for (int k = 0; k < 2; ++k) {
        const int n = tid + k * 256;
        const int* map_n = mapping + n * TUP;
        int a = 0;
        #pragma unroll
        for (int t = 0; t < TUP; ++t) {
            const int j = map_n[t];
            a = (a << 1) | ((packed[j >> 5] >> (j & 31)) & 1);
        }
        const int idx = (n << 16) | a;
        const int c = counts[idx];
        if (c > 0) { resp += sums[idx]; cnt += c; }
    }
    #pragma unroll
    for (int off = 32; off > 0; off >>= 1) {
        resp += __shfl_down(resp, off, 64);
        cnt  += __shfl_down(cnt,  off, 64);
    }
    if (lane == 0) { s_resp[wv] = resp; s_cnt[wv] = cnt; }
    __syncthreads();
    if (tid == 0) {
        float r = s_resp[0] + s_resp[1] + s_resp[2] + s_resp[3];
        int   c = s_cnt[0] + s_cnt[1] + s_cnt[2] + s_cnt[3];
        out[blockIdx.x] = (c > 0) ? (r / (float)c) : 0.0f;
    }
}

extern "C" void kernel_launch(void* const* d_in, const int* in_sizes, int n_in,
                              void* d_out, int out_size, void* d_ws, size_t ws_size,
                              hipStream_t stream) {
    (void)in_sizes; (void)n_in; (void)out_size;
    const int*   input   = (const int*)d_in[0];
    const int*   mapping = (const int*)d_in[1];
    const int*   counts  = (const int*)d_in[2];
    const float* sums    = (const float*)d_in[3];
    float*       out     = (float*)d_out;

    if (ws_size >= WS_NEED) {
        unsigned short*     addr_ws = (unsigned short*)d_ws;
        unsigned long long* acc     = (unsigned long long*)((char*)d_ws + ACC_OFF);
        zero_acc_kernel<<<BATCH / 256, 256, 0, stream>>>(acc);
        phaseA_kernel<<<BATCH / SPB_A, 256, 0, stream>>>(input, mapping, addr_ws);
        phaseB_kernel<<<NEUR * QSPLIT, 256, 0, stream>>>(counts, sums, addr_ws, acc);
        phaseC_kernel<<<BATCH / 256, 256, 0, stream>>>(acc, out);
    } else {
        wisard_direct_kernel<<<BATCH, 256, 0, stream>>>(input, mapping, counts, sums, out);
    }
}